// Round 1
// baseline (250.424 us; speedup 1.0000x reference)
//
#include <hip/hip_runtime.h>
#include <hip/hip_bf16.h>
#include <hip/hip_cooperative_groups.h>
#include <math.h>

// SoftDPPCausalSelfAttention — MI355X (gfx950)
//
// DPP penalty is a numerical constant (det underflow):
//   penalty = -0.01 * 16384 * log(1e-8) = 3018.0443
//
// Round-15: FUSE all three kernels into ONE cooperative kernel.
// Evidence: steady state = 41us ws re-poison (its own roofline) + ~5us
// restores + ~52us kernels+gaps; each kernel is at its latency floor
// (R7-R13), and R13 showed a single extra graph node costs ~+24us.
// => the remaining lever is NODE COUNT. 3 nodes -> 1 cooperative node
// with two grid.sync() barriers (each ~2-5us vs ~10us+ per node gap).
//
// Fused layout: 512 blocks x 256 thr, __launch_bounds__(256,2)
//   (VGPR<=256 -> 2 blk/CU; LDS 36864B x2 = 73.7KB <= 160KB -> resident)
//   Phase 1: qkv GEMM, 64x96 tiles -> exactly 512 tiles, 1/block.
//   Phase 2: attention, 256 units on blocks 0-255 (rest idle to barrier).
//   Phase 3: proj GEMM, 32x64 tiles -> exactly 512 tiles, 1/block.
// Fallback: if cooperative launch is rejected, run the verified R12
// 3-kernel path (byte-identical bodies kept below).
//
// ws: [0,6.29M) qkv bf16 [2048][1536] (V region unused)
//     [6.29M,8.39M) vt_g bf16 [64 bh][64 d][256 j]
//     [8.39M,10.49M) y bf16 [2048][512]

#define BT 2048
#define TSEQ 256
#define CDIM 512
#define QKVC 1536

namespace cg = cooperative_groups;

typedef __attribute__((ext_vector_type(8))) short bf16x8;
typedef __attribute__((ext_vector_type(4))) float f32x4;

__device__ __forceinline__ unsigned short b16(float f) {
  return __builtin_bit_cast(unsigned short, __float2bfloat16(f));
}

// ---------------------------------------------------------------------------
// FUSED kernel: qkv -> grid.sync -> attn -> grid.sync -> proj
// ---------------------------------------------------------------------------
__global__ __launch_bounds__(256, 2) void fused_all(
    const float* __restrict__ X, const float* __restrict__ W_attn,
    const float* __restrict__ b_attn, const float* __restrict__ W_proj,
    const float* __restrict__ b_proj, float* __restrict__ out,
    unsigned short* __restrict__ qkv, unsigned short* __restrict__ vt,
    unsigned short* __restrict__ y) {
  // Shared arena: max(phase1 21760, phase2 36864, phase3 13056) bytes.
  __shared__ __align__(16) char smem[36864];

  const int t   = threadIdx.x;
  const int bid = blockIdx.x;
  const int w   = t >> 6, l = t & 63;

  cg::grid_group grid = cg::this_grid();

  if (bid == 0 && t == 0) {
    const double log_1em8 = -18.420680743952367;
    out[(size_t)BT * CDIM] = (float)(-0.01 * (16384.0 * log_1em8)); // 3018.0443
  }

  // ===== Phase 1: qkv = x @ W_attn^T + b  (64x96 tile, BK=64) ==============
  {
    unsigned short (*a_s)[68] = (unsigned short(*)[68])smem;           // 64x68
    unsigned short (*b_s)[68] = (unsigned short(*)[68])(smem + 8704);  // 96x68

    const int mi = bid & 31, ni = bid >> 5;   // 32 m-tiles x 16 n-tiles
    const int m0 = mi * 64, n0 = ni * 96;
    const int wm = (w >> 1) * 32, wn = (w & 1) * 48;

    f32x4 acc[2][3];
#pragma unroll
    for (int i = 0; i < 2; i++)
#pragma unroll
      for (int j = 0; j < 3; j++) acc[i][j] = (f32x4){0.f, 0.f, 0.f, 0.f};

    float4 pa[4], pb[6];
    auto prefetch = [&](int k0) {
#pragma unroll
      for (int u = 0; u < 4; u++) {
        const int id = t + u * 256;
        const int r  = id >> 4;
        const int c4 = (id & 15) << 2;
        pa[u] = *(const float4*)&X[(size_t)(m0 + r) * CDIM + k0 + c4];
      }
#pragma unroll
      for (int u = 0; u < 6; u++) {
        const int id = t + u * 256;
        const int r  = id >> 4;
        const int c4 = (id & 15) << 2;
        pb[u] = *(const float4*)&W_attn[(size_t)(n0 + r) * CDIM + k0 + c4];
      }
    };

    prefetch(0);
    for (int kb = 0; kb < CDIM / 64; kb++) {
      __syncthreads();
#pragma unroll
      for (int u = 0; u < 4; u++) {
        const int id = t + u * 256;
        const int r  = id >> 4;
        const int c4 = (id & 15) << 2;
        ushort4 ah;
        ah.x = b16(pa[u].x); ah.y = b16(pa[u].y); ah.z = b16(pa[u].z); ah.w = b16(pa[u].w);
        *(ushort4*)&a_s[r][c4] = ah;
      }
#pragma unroll
      for (int u = 0; u < 6; u++) {
        const int id = t + u * 256;
        const int r  = id >> 4;
        const int c4 = (id & 15) << 2;
        ushort4 bh;
        bh.x = b16(pb[u].x); bh.y = b16(pb[u].y); bh.z = b16(pb[u].z); bh.w = b16(pb[u].w);
        *(ushort4*)&b_s[r][c4] = bh;
      }
      __syncthreads();
      if (kb + 1 < CDIM / 64) prefetch((kb + 1) * 64);

#pragma unroll
      for (int ks = 0; ks < 2; ks++) {
        const int fr = l & 15;
        const int fk = ks * 32 + ((l >> 4) << 3);
        bf16x8 fa[2], fb[3];
#pragma unroll
        for (int mt = 0; mt < 2; mt++) fa[mt] = *(const bf16x8*)&a_s[wm + mt * 16 + fr][fk];
#pragma unroll
        for (int nt = 0; nt < 3; nt++) fb[nt] = *(const bf16x8*)&b_s[wn + nt * 16 + fr][fk];
#pragma unroll
        for (int mt = 0; mt < 2; mt++)
#pragma unroll
          for (int nt = 0; nt < 3; nt++)
            acc[mt][nt] = __builtin_amdgcn_mfma_f32_16x16x32_bf16(fa[mt], fb[nt], acc[mt][nt], 0, 0, 0);
      }
    }

    const int cl = l & 15, rq = (l >> 4) << 2;
#pragma unroll
    for (int nt = 0; nt < 3; nt++) {
      const int colb = n0 + wn + nt * 16;   // 16-aligned; region uniform per nt
      const int col  = colb + cl;
      const float bv = b_attn[col];
      if (colb < 1024) {
        const float scale = (colb < 512) ? 0.125f : 1.0f;   // Q pre-scale
#pragma unroll
        for (int mt = 0; mt < 2; mt++) {
          const int row = m0 + wm + mt * 16 + rq;
#pragma unroll
          for (int r = 0; r < 4; r++)
            qkv[(size_t)(row + r) * QKVC + col] = b16((acc[mt][nt][r] + bv) * scale);
        }
      } else {
        // V transposed: vt[(b*8+h)*64 + d][j]; 4 acc regs = 4 consecutive j.
        const int hcol = col - 1024;
        const int hh = hcol >> 6, d = hcol & 63;
#pragma unroll
        for (int mt = 0; mt < 2; mt++) {
          const int row = m0 + wm + mt * 16 + rq;
          const int bb = row >> 8, j = row & 255;
          ushort4 o;
          o.x = b16(acc[mt][nt][0] + bv);
          o.y = b16(acc[mt][nt][1] + bv);
          o.z = b16(acc[mt][nt][2] + bv);
          o.w = b16(acc[mt][nt][3] + bv);
          *(ushort4*)&vt[(((size_t)(bb * 8 + hh) * 64 + d) << 8) + j] = o;
        }
      }
    }
  }

  grid.sync();

  // ===== Phase 2: MFMA flash attention (blocks 0..255) =====================
  if (bid < 256) {
    unsigned short (*k_s)[72]      = (unsigned short(*)[72])smem;              //  9216
    unsigned short (*vt_s)[72]     = (unsigned short(*)[72])(smem + 9216);     //  9216
    unsigned short (*q_s2)[32][72] = (unsigned short(*)[32][72])(smem + 18432);//  9216
    unsigned short (*p_s)[16][72]  = (unsigned short(*)[16][72])(smem + 27648);//  9216

    const int qp = bid & 3;             // 0..3: qt pair (2qp, 2qp+1)
    const int bh = bid >> 2;            // 0..63
    const int b  = bh >> 3, h = bh & 7;
    const int half = w >> 1;
    const int ww   = w & 1;
    const int qt = qp * 2 + half;
    const int q0 = qt * 32;
    const size_t rowbase = (size_t)b * TSEQ * QKVC + h * 64;
    const size_t vtb = (size_t)bh << 14;
    const float NEG = -1e30f;

#pragma unroll
    for (int u = 0; u < 2; u++) {
      const int id = t + u * 256;
      const int rg = id >> 3, c8 = (id & 7) << 3;
      const int hf = rg >> 5, row = rg & 31;
      const int qrow = (qp * 2 + hf) * 32 + row;
      *(uint4*)&q_s2[hf][row][c8] =
          *(const uint4*)(qkv + rowbase + (size_t)qrow * QKVC + c8);
    }
    __syncthreads();

    const int m  = l & 15;
    const int q4 = l >> 4;
    const int ko = q4 << 3;

    bf16x8 qf[2];
#pragma unroll
    for (int kb = 0; kb < 2; kb++)
      qf[kb] = *(const bf16x8*)&q_s2[half][ww * 16 + m][kb * 32 + ko];

    f32x4 acc_y[4];
    float m_i[4], Zp[4];
#pragma unroll
    for (int r = 0; r < 4; r++) {
      acc_y[r] = (f32x4){0.f, 0.f, 0.f, 0.f};
      m_i[r] = NEG; Zp[r] = 0.f;
    }

    const int ntiles = qp + 1;

    uint4 pk[2], pv[2];
    auto loadKV = [&](int jt) {
#pragma unroll
      for (int u = 0; u < 2; u++) {
        const int id = t + u * 256;
        const int r = id >> 3, c8 = (id & 7) << 3;
        pk[u] = *(const uint4*)(qkv + rowbase + (size_t)(jt * 64 + r) * QKVC + 512 + c8);
        pv[u] = *(const uint4*)(vt + vtb + ((size_t)r << 8) + jt * 64 + c8);
      }
    };

    loadKV(0);
    for (int jt = 0; jt < ntiles; jt++) {
      __syncthreads();
#pragma unroll
      for (int u = 0; u < 2; u++) {
        const int id = t + u * 256;
        const int r = id >> 3, c8 = (id & 7) << 3;
        *(uint4*)&k_s[r][c8]  = pk[u];
        *(uint4*)&vt_s[r][c8] = pv[u];
      }
      __syncthreads();
      if (jt + 1 < ntiles) loadKV(jt + 1);

      f32x4 s[4];
#pragma unroll
      for (int nt = 0; nt < 4; nt++) s[nt] = (f32x4){0.f, 0.f, 0.f, 0.f};
#pragma unroll
      for (int nt = 0; nt < 4; nt++)
#pragma unroll
        for (int kb = 0; kb < 2; kb++) {
          const bf16x8 kf = *(const bf16x8*)&k_s[nt * 16 + m][kb * 32 + ko];
          s[nt] = __builtin_amdgcn_mfma_f32_16x16x32_bf16(qf[kb], kf, s[nt], 0, 0, 0);
        }

      const bool diag = (jt == ntiles - 1);
#pragma unroll
      for (int reg = 0; reg < 4; reg++) {
        const int i = q0 + ww * 16 + q4 * 4 + reg;
        float pvv[4];
        float vmax = NEG;
#pragma unroll
        for (int nt = 0; nt < 4; nt++) {
          float sv = s[nt][reg];
          if (diag && (jt * 64 + nt * 16 + m) > i) sv = NEG;
          pvv[nt] = sv;
          vmax = fmaxf(vmax, sv);
        }
        vmax = fmaxf(vmax, __shfl_xor(vmax, 1));
        vmax = fmaxf(vmax, __shfl_xor(vmax, 2));
        vmax = fmaxf(vmax, __shfl_xor(vmax, 4));
        vmax = fmaxf(vmax, __shfl_xor(vmax, 8));
        const float mnew  = fmaxf(m_i[reg], vmax);
        const float alpha = __expf(m_i[reg] - mnew);
        m_i[reg] = mnew;
        float zs = 0.f;
#pragma unroll
        for (int nt = 0; nt < 4; nt++) {
          const float p = __expf(pvv[nt] - mnew);
          p_s[w][q4 * 4 + reg][nt * 16 + m] = b16(p);
          zs += p;
        }
        Zp[reg] = Zp[reg] * alpha + zs;
#pragma unroll
        for (int nt2 = 0; nt2 < 4; nt2++) acc_y[nt2][reg] *= alpha;
      }
      __syncthreads();   // cross-lane P round-trip needs a real barrier

#pragma unroll
      for (int kb2 = 0; kb2 < 2; kb2++) {
        const bf16x8 pf = *(const bf16x8*)&p_s[w][m][kb2 * 32 + ko];
#pragma unroll
        for (int nt2 = 0; nt2 < 4; nt2++) {
          const bf16x8 vf = *(const bf16x8*)&vt_s[nt2 * 16 + m][kb2 * 32 + ko];
          acc_y[nt2] = __builtin_amdgcn_mfma_f32_16x16x32_bf16(pf, vf, acc_y[nt2], 0, 0, 0);
        }
      }
    }

#pragma unroll
    for (int reg = 0; reg < 4; reg++) {
      float z = Zp[reg];
      z += __shfl_xor(z, 1);
      z += __shfl_xor(z, 2);
      z += __shfl_xor(z, 4);
      z += __shfl_xor(z, 8);
      const float inv = 1.0f / z;
      const int i = q0 + ww * 16 + q4 * 4 + reg;
#pragma unroll
      for (int nt2 = 0; nt2 < 4; nt2++)
        y[((size_t)(b * TSEQ + i)) * CDIM + h * 64 + nt2 * 16 + m] =
            b16(acc_y[nt2][reg] * inv);
    }
  }

  grid.sync();

  // ===== Phase 3: out = y @ W_proj^T + b  (32x64 tile, 512 tiles) ==========
  {
    unsigned short (*a_s)[68] = (unsigned short(*)[68])smem;           // 32x68
    unsigned short (*b_s)[68] = (unsigned short(*)[68])(smem + 4352);  // 64x68

    const int mi = bid & 63, ni = bid >> 6;   // 64 m-tiles x 8 n-tiles
    const int m0 = mi * 32, n0 = ni * 64;
    const int wm = (w >> 1) * 16, wn = (w & 1) * 32;

    f32x4 acc[2];
#pragma unroll
    for (int j = 0; j < 2; j++) acc[j] = (f32x4){0.f, 0.f, 0.f, 0.f};

    uint4  pa;
    float4 pb[4];
    auto prefetch = [&](int k0) {
      {
        const int r = t >> 3, c8 = (t & 7) << 3;
        pa = *(const uint4*)(y + (size_t)(m0 + r) * CDIM + k0 + c8);
      }
#pragma unroll
      for (int u = 0; u < 4; u++) {
        const int id = t + u * 256;
        const int r = id >> 4, c4 = (id & 15) << 2;
        pb[u] = *(const float4*)&W_proj[(size_t)(n0 + r) * CDIM + k0 + c4];
      }
    };

    prefetch(0);
    for (int kb = 0; kb < CDIM / 64; kb++) {
      __syncthreads();
      {
        const int r = t >> 3, c8 = (t & 7) << 3;
        *(uint4*)&a_s[r][c8] = pa;
      }
#pragma unroll
      for (int u = 0; u < 4; u++) {
        const int id = t + u * 256;
        const int r = id >> 4, c4 = (id & 15) << 2;
        ushort4 bh;
        bh.x = b16(pb[u].x); bh.y = b16(pb[u].y); bh.z = b16(pb[u].z); bh.w = b16(pb[u].w);
        *(ushort4*)&b_s[r][c4] = bh;
      }
      __syncthreads();
      if (kb + 1 < CDIM / 64) prefetch((kb + 1) * 64);

#pragma unroll
      for (int ks = 0; ks < 2; ks++) {
        const int fr = l & 15;
        const int fk = ks * 32 + ((l >> 4) << 3);
        const bf16x8 fa = *(const bf16x8*)&a_s[wm + fr][fk];
        bf16x8 fb2[2];
#pragma unroll
        for (int nt = 0; nt < 2; nt++) fb2[nt] = *(const bf16x8*)&b_s[wn + nt * 16 + fr][fk];
#pragma unroll
        for (int nt = 0; nt < 2; nt++)
          acc[nt] = __builtin_amdgcn_mfma_f32_16x16x32_bf16(fa, fb2[nt], acc[nt], 0, 0, 0);
      }
    }

    const int cl = l & 15, rq = (l >> 4) << 2;
#pragma unroll
    for (int nt = 0; nt < 2; nt++) {
      const int col = n0 + wn + nt * 16 + cl;
      const float bv = b_proj[col];
      const int row = m0 + wm + rq;
#pragma unroll
      for (int r = 0; r < 4; r++)
        out[(size_t)(row + r) * CDIM + col] = acc[nt][r] + bv;
    }
  }
}

// ===========================================================================
// FALLBACK path: verified R12 3-kernel pipeline (byte-identical bodies).
// Used only if the cooperative launch is rejected by the runtime.
// ===========================================================================
__global__ __launch_bounds__(256) void qkv_mfma(
    const float* __restrict__ X, const float* __restrict__ W,
    const float* __restrict__ bias, unsigned short* __restrict__ C,
    unsigned short* __restrict__ VT) {
  __shared__ unsigned short a_s[64][68];
  __shared__ unsigned short b_s[64][68];

  const int t  = threadIdx.x;
  const int m0 = blockIdx.x * 64;
  const int n0 = blockIdx.y * 64;
  const int w  = t >> 6, l = t & 63;
  const int wm = (w >> 1) * 32, wn = (w & 1) * 32;

  f32x4 acc[2][2];
#pragma unroll
  for (int i = 0; i < 2; i++)
#pragma unroll
    for (int j = 0; j < 2; j++) acc[i][j] = (f32x4){0.f, 0.f, 0.f, 0.f};

  float4 pa[4], pb[4];
  auto prefetch = [&](int k0) {
#pragma unroll
    for (int u = 0; u < 4; u++) {
      const int id = t + u * 256;
      const int r  = id >> 4;
      const int c4 = (id & 15) << 2;
      pa[u] = *(const float4*)&X[(size_t)(m0 + r) * CDIM + k0 + c4];
      pb[u] = *(const float4*)&W[(size_t)(n0 + r) * CDIM + k0 + c4];
    }
  };

  prefetch(0);
  for (int kb = 0; kb < CDIM / 64; kb++) {
    __syncthreads();
#pragma unroll
    for (int u = 0; u < 4; u++) {
      const int id = t + u * 256;
      const int r  = id >> 4;
      const int c4 = (id & 15) << 2;
      ushort4 ah;
      ah.x = b16(pa[u].x); ah.y = b16(pa[u].y); ah.z = b16(pa[u].z); ah.w = b16(pa[u].w);
      *(ushort4*)&a_s[r][c4] = ah;
      ushort4 bh;
      bh.x = b16(pb[u].x); bh.y = b16(pb[u].y); bh.z = b16(pb[u].z); bh.w = b16(pb[u].w);
      *(ushort4*)&b_s[r][c4] = bh;
    }
    __syncthreads();
    if (kb + 1 < CDIM / 64) prefetch((kb + 1) * 64);

#pragma unroll
    for (int ks = 0; ks < 2; ks++) {
      const int fr = l & 15;
      const int fk = ks * 32 + ((l >> 4) << 3);
      bf16x8 fa[2], fb[2];
#pragma unroll
      for (int mt = 0; mt < 2; mt++) fa[mt] = *(const bf16x8*)&a_s[wm + mt * 16 + fr][fk];
#pragma unroll
      for (int nt = 0; nt < 2; nt++) fb[nt] = *(const bf16x8*)&b_s[wn + nt * 16 + fr][fk];
#pragma unroll
      for (int mt = 0; mt < 2; mt++)
#pragma unroll
        for (int nt = 0; nt < 2; nt++)
          acc[mt][nt] = __builtin_amdgcn_mfma_f32_16x16x32_bf16(fa[mt], fb[nt], acc[mt][nt], 0, 0, 0);
    }
  }

  const int cl = l & 15, rq = (l >> 4) << 2;
  if (n0 < 1024) {
    const float scale = (n0 < 512) ? 0.125f : 1.0f;
#pragma unroll
    for (int nt = 0; nt < 2; nt++) {
      const int col = n0 + wn + nt * 16 + cl;
      const float bv = bias[col];
#pragma unroll
      for (int mt = 0; mt < 2; mt++) {
        const int row = m0 + wm + mt * 16 + rq;
#pragma unroll
        for (int r = 0; r < 4; r++)
          C[(size_t)(row + r) * QKVC + col] = b16((acc[mt][nt][r] + bv) * scale);
      }
    }
  } else {
#pragma unroll
    for (int nt = 0; nt < 2; nt++) {
      const int col  = n0 + wn + nt * 16 + cl;
      const float bv = bias[col];
      const int hcol = col - 1024;
      const int h = hcol >> 6, d = hcol & 63;
#pragma unroll
      for (int mt = 0; mt < 2; mt++) {
        const int row = m0 + wm + mt * 16 + rq;
        const int b = row >> 8, j = row & 255;
        ushort4 o;
        o.x = b16(acc[mt][nt][0] + bv);
        o.y = b16(acc[mt][nt][1] + bv);
        o.z = b16(acc[mt][nt][2] + bv);
        o.w = b16(acc[mt][nt][3] + bv);
        *(ushort4*)&VT[(((size_t)(b * 8 + h) * 64 + d) << 8) + j] = o;
      }
    }
  }
}

__global__ __launch_bounds__(256) void attn_mfma(
    const unsigned short* __restrict__ qkv, const unsigned short* __restrict__ VT,
    unsigned short* __restrict__ y) {
  __shared__ unsigned short k_s[64][72];
  __shared__ unsigned short vt_s[64][72];
  __shared__ unsigned short q_s2[2][32][72];
  __shared__ unsigned short p_s[4][16][72];

  const int t  = threadIdx.x;
  const int qp = blockIdx.x;
  const int bh = blockIdx.y;
  const int b  = bh >> 3, h = bh & 7;
  const int w  = t >> 6, l = t & 63;
  const int half = w >> 1;
  const int ww   = w & 1;
  const int qt = qp * 2 + half;
  const int q0 = qt * 32;
  const size_t rowbase = (size_t)b * TSEQ * QKVC + h * 64;
  const size_t vtb = (size_t)bh << 14;
  const float NEG = -1e30f;

#pragma unroll
  for (int u = 0; u < 2; u++) {
    const int id = t + u * 256;
    const int rg = id >> 3, c8 = (id & 7) << 3;
    const int hf = rg >> 5, row = rg & 31;
    const int qrow = (qp * 2 + hf) * 32 + row;
    *(uint4*)&q_s2[hf][row][c8] =
        *(const uint4*)(qkv + rowbase + (size_t)qrow * QKVC + c8);
  }
  __syncthreads();

  const int m  = l & 15;
  const int q4 = l >> 4;
  const int ko = q4 << 3;

  bf16x8 qf[2];
#pragma unroll
  for (int kb = 0; kb < 2; kb++)
    qf[kb] = *(const bf16x8*)&q_s2[half][ww * 16 + m][kb * 32 + ko];

  f32x4 acc_y[4];
  float m_i[4], Zp[4];
#pragma unroll
  for (int r = 0; r < 4; r++) {
    acc_y[r] = (f32x4){0.f, 0.f, 0.f, 0.f};
    m_i[r] = NEG; Zp[r] = 0.f;
  }

  const int ntiles = qp + 1;

  uint4 pk[2], pv[2];
  auto loadKV = [&](int jt) {
#pragma unroll
    for (int u = 0; u < 2; u++) {
      const int id = t + u * 256;
      const int r = id >> 3, c8 = (id & 7) << 3;
      pk[u] = *(const uint4*)(qkv + rowbase + (size_t)(jt * 64 + r) * QKVC + 512 + c8);
      pv[u] = *(const uint4*)(VT + vtb + ((size_t)r << 8) + jt * 64 + c8);
    }
  };

  loadKV(0);
  for (int jt = 0; jt < ntiles; jt++) {
    __syncthreads();
#pragma unroll
    for (int u = 0; u < 2; u++) {
      const int id = t + u * 256;
      const int r = id >> 3, c8 = (id & 7) << 3;
      *(uint4*)&k_s[r][c8]  = pk[u];
      *(uint4*)&vt_s[r][c8] = pv[u];
    }
    __syncthreads();
    if (jt + 1 < ntiles) loadKV(jt + 1);

    f32x4 s[4];
#pragma unroll
    for (int nt = 0; nt < 4; nt++) s[nt] = (f32x4){0.f, 0.f, 0.f, 0.f};
#pragma unroll
    for (int nt = 0; nt < 4; nt++)
#pragma unroll
      for (int kb = 0; kb < 2; kb++) {
        const bf16x8 kf = *(const bf16x8*)&k_s[nt * 16 + m][kb * 32 + ko];
        s[nt] = __builtin_amdgcn_mfma_f32_16x16x32_bf16(qf[kb], kf, s[nt], 0, 0, 0);
      }

    const bool diag = (jt == ntiles - 1);
#pragma unroll
    for (int reg = 0; reg < 4; reg++) {
      const int i = q0 + ww * 16 + q4 * 4 + reg;
      float pvv[4];
      float vmax = NEG;
#pragma unroll
      for (int nt = 0; nt < 4; nt++) {
        float sv = s[nt][reg];
        if (diag && (jt * 64 + nt * 16 + m) > i) sv = NEG;
        pvv[nt] = sv;
        vmax = fmaxf(vmax, sv);
      }
      vmax = fmaxf(vmax, __shfl_xor(vmax, 1));
      vmax = fmaxf(vmax, __shfl_xor(vmax, 2));
      vmax = fmaxf(vmax, __shfl_xor(vmax, 4));
      vmax = fmaxf(vmax, __shfl_xor(vmax, 8));
      const float mnew  = fmaxf(m_i[reg], vmax);
      const float alpha = __expf(m_i[reg] - mnew);
      m_i[reg] = mnew;
      float zs = 0.f;
#pragma unroll
      for (int nt = 0; nt < 4; nt++) {
        const float p = __expf(pvv[nt] - mnew);
        p_s[w][q4 * 4 + reg][nt * 16 + m] = b16(p);
        zs += p;
      }
      Zp[reg] = Zp[reg] * alpha + zs;
#pragma unroll
      for (int nt2 = 0; nt2 < 4; nt2++) acc_y[nt2][reg] *= alpha;
    }
    __syncthreads();

#pragma unroll
    for (int kb2 = 0; kb2 < 2; kb2++) {
      const bf16x8 pf = *(const bf16x8*)&p_s[w][m][kb2 * 32 + ko];
#pragma unroll
      for (int nt2 = 0; nt2 < 4; nt2++) {
        const bf16x8 vf = *(const bf16x8*)&vt_s[nt2 * 16 + m][kb2 * 32 + ko];
        acc_y[nt2] = __builtin_amdgcn_mfma_f32_16x16x32_bf16(pf, vf, acc_y[nt2], 0, 0, 0);
      }
    }
  }

#pragma unroll
  for (int reg = 0; reg < 4; reg++) {
    float z = Zp[reg];
    z += __shfl_xor(z, 1);
    z += __shfl_xor(z, 2);
    z += __shfl_xor(z, 4);
    z += __shfl_xor(z, 8);
    const float inv = 1.0f / z;
    const int i = q0 + ww * 16 + q4 * 4 + reg;
#pragma unroll
    for (int nt2 = 0; nt2 < 4; nt2++)
      y[((size_t)(b * TSEQ + i)) * CDIM + h * 64 + nt2 * 16 + m] =
          b16(acc_y[nt2][reg] * inv);
  }
}

__global__ __launch_bounds__(256) void proj_mfma(
    const unsigned short* __restrict__ A, const float* __restrict__ B,
    const float* __restrict__ bias, float* __restrict__ C) {
  __shared__ unsigned short a_s[32][68];
  __shared__ unsigned short b_s[64][68];

  const int t  = threadIdx.x;
  if (blockIdx.x == 0 && blockIdx.y == 0 && t == 0) {
    const double log_1em8 = -18.420680743952367;
    C[(size_t)BT * CDIM] = (float)(-0.01 * (16384.0 * log_1em8));
  }
  const int m0 = blockIdx.x * 32;
  const int n0 = blockIdx.y * 64;
  const int w  = t >> 6, l = t & 63;
  const int wm = (w >> 1) * 16, wn = (w & 1) * 32;

  f32x4 acc[2];
#pragma unroll
  for (int j = 0; j < 2; j++) acc[j] = (f32x4){0.f, 0.f, 0.f, 0.f};

  uint4  pa;
  float4 pb[4];
  auto prefetch = [&](int k0) {
    {
      const int r = t >> 3, c8 = (t & 7) << 3;
      pa = *(const uint4*)(A + (size_t)(m0 + r) * CDIM + k0 + c8);
    }
#pragma unroll
    for (int u = 0; u < 4; u++) {
      const int id = t + u * 256;
      const int r = id >> 4, c4 = (id & 15) << 2;
      pb[u] = *(const float4*)&B[(size_t)(n0 + r) * CDIM + k0 + c4];
    }
  };

  prefetch(0);
  for (int kb = 0; kb < CDIM / 64; kb++) {
    __syncthreads();
    {
      const int r = t >> 3, c8 = (t & 7) << 3;
      *(uint4*)&a_s[r][c8] = pa;
    }
#pragma unroll
    for (int u = 0; u < 4; u++) {
      const int id = t + u * 256;
      const int r = id >> 4, c4 = (id & 15) << 2;
      ushort4 bh;
      bh.x = b16(pb[u].x); bh.y = b16(pb[u].y); bh.z = b16(pb[u].z); bh.w = b16(pb[u].w);
      *(ushort4*)&b_s[r][c4] = bh;
    }
    __syncthreads();
    if (kb + 1 < CDIM / 64) prefetch((kb + 1) * 64);

#pragma unroll
    for (int ks = 0; ks < 2; ks++) {
      const int fr = l & 15;
      const int fk = ks * 32 + ((l >> 4) << 3);
      const bf16x8 fa = *(const bf16x8*)&a_s[wm + fr][fk];
      bf16x8 fb2[2];
#pragma unroll
      for (int nt = 0; nt < 2; nt++) fb2[nt] = *(const bf16x8*)&b_s[wn + nt * 16 + fr][fk];
#pragma unroll
      for (int nt = 0; nt < 2; nt++)
        acc[nt] = __builtin_amdgcn_mfma_f32_16x16x32_bf16(fa, fb2[nt], acc[nt], 0, 0, 0);
    }
  }

  const int cl = l & 15, rq = (l >> 4) << 2;
#pragma unroll
  for (int nt = 0; nt < 2; nt++) {
    const int col = n0 + wn + nt * 16 + cl;
    const float bv = bias[col];
    const int row = m0 + wm + rq;
#pragma unroll
    for (int r = 0; r < 4; r++)
      C[(size_t)(row + r) * CDIM + col] = acc[nt][r] + bv;
  }
}

extern "C" void kernel_launch(void* const* d_in, const int* in_sizes, int n_in,
                              void* d_out, int out_size, void* d_ws, size_t ws_size,
                              hipStream_t stream) {
  const float* x      = (const float*)d_in[0];
  const float* W_attn = (const float*)d_in[1];
  const float* b_attn = (const float*)d_in[2];
  const float* W_proj = (const float*)d_in[3];
  const float* b_proj = (const float*)d_in[4];
  float* out = (float*)d_out;

  char* wsb = (char*)d_ws;
  unsigned short* qkv_bf = (unsigned short*)wsb;              // 6.29 MB (Q,K)
  unsigned short* vt_bf  = (unsigned short*)(wsb + 6291456);  // 2.10 MB (V^T)
  unsigned short* y_bf   = (unsigned short*)(wsb + 8388608);  // 2.10 MB

  void* args[9] = {
      (void*)&x, (void*)&W_attn, (void*)&b_attn, (void*)&W_proj, (void*)&b_proj,
      (void*)&out, (void*)&qkv_bf, (void*)&vt_bf, (void*)&y_bf};

  hipError_t e = hipLaunchCooperativeKernel(
      (const void*)fused_all, dim3(512, 1, 1), dim3(256, 1, 1), args, 0, stream);

  if (e != hipSuccess) {
    (void)hipGetLastError();  // clear sticky error; fall back to R12 path
    qkv_mfma<<<dim3(32, 24), 256, 0, stream>>>(x, W_attn, b_attn, qkv_bf, vt_bf);
    attn_mfma<<<dim3(4, 64), 256, 0, stream>>>(qkv_bf, vt_bf, y_bf);
    proj_mfma<<<dim3(64, 8), 256, 0, stream>>>(y_bf, W_proj, b_proj, out);
  }
}

// Round 2
// 119.747 us; speedup vs baseline: 2.0913x; 2.0913x over previous
//
#include <hip/hip_runtime.h>
#include <hip/hip_bf16.h>
#include <math.h>

// SoftDPPCausalSelfAttention — MI355X (gfx950)
//
// DPP penalty is a numerical constant (det underflow):
//   penalty = -0.01 * 16384 * log(1e-8) = 3018.0443
//
// Round-16: 2-node pipeline WITHOUT grid sync.
// R15 post-mortem: cooperative grid.sync() measured ~50-80us per barrier at
// 512 blocks (fused_all 176us, MfmaUtil 1%) — cross-XCD barrier is far more
// expensive than predicted. Cooperative launch abandoned.
// This round removes a node the sync-free way: block (qp,bh) computes its own
// Q tile + K|V tiles for ITS head directly into LDS (64x64x512 / 64x128x512
// MFMA GEMMs; 2.5x redundant K/V compute ~ 3 GF chip-wide, cheap), then runs
// the verified attention body reading Q/K/V straight from LDS. No qkv/vt
// workspace round-trip, no staging loop in the jt iteration. proj stays a
// separate node (needs all heads of y).
//
// Kernel 1: qkv_attn_fused  grid(4,64) x 256thr, LDS 115,200 B (1 blk/CU).
// Kernel 2: proj_mfma       grid(64,8) x 256thr (verified R12 body).
//
// ws: [0, 2.10M) y bf16 [2048][512]

#define BT 2048
#define TSEQ 256
#define CDIM 512

typedef __attribute__((ext_vector_type(8))) short bf16x8;
typedef __attribute__((ext_vector_type(4))) float f32x4;

__device__ __forceinline__ unsigned short b16(float f) {
  return __builtin_bit_cast(unsigned short, __float2bfloat16(f));
}

// ---------------------------------------------------------------------------
// Fused per-head QKV GEMM + flash attention.
// Block (qp, bh): owns q-tiles 2qp,2qp+1 (tokens qp*64..qp*64+63) of head h,
// batch b. Computes K,V for tokens 0..ntiles*64-1 (ntiles=qp+1) and Q for its
// own 64 tokens, all into LDS, then the verified attention body.
// ---------------------------------------------------------------------------
__global__ __launch_bounds__(256) void qkv_attn_fused(
    const float* __restrict__ X, const float* __restrict__ W_attn,
    const float* __restrict__ b_attn, unsigned short* __restrict__ y) {
  __shared__ unsigned short a_s[64][68];     //  8704 B  GEMM A staging
  __shared__ unsigned short b_s[128][68];    // 17408 B  GEMM B staging
  __shared__ unsigned short q_s[64][72];     //  9216 B  Q (scaled, biased)
  __shared__ unsigned short k_all[256][72];  // 36864 B  K [token][d]
  __shared__ unsigned short vt_all[64][264]; // 33792 B  V^T [d][token]
  __shared__ unsigned short p_s[4][16][72];  //  9216 B  per-wave P tile

  const int t  = threadIdx.x;
  const int qp = blockIdx.x;          // 0..3
  const int bh = blockIdx.y;          // 0..63
  const int b  = bh >> 3, h = bh & 7;
  const int w  = t >> 6, l = t & 63;
  const int ntiles = qp + 1;

  const int fr = l & 15;
  const int cl = l & 15, rq = (l >> 4) << 2;

  // ===== Phase A1: K|V tiles (64 tokens x [64 K-d | 64 V-d]) ===============
  {
    const int wm = (w >> 1) * 32, wn = (w & 1) * 64;
    for (int jt = 0; jt < ntiles; jt++) {
      f32x4 acc[2][4];
#pragma unroll
      for (int i = 0; i < 2; i++)
#pragma unroll
        for (int j = 0; j < 4; j++) acc[i][j] = (f32x4){0.f, 0.f, 0.f, 0.f};

      float4 pa[4], pb[8];
      auto prefetch = [&](int k0) {
#pragma unroll
        for (int u = 0; u < 4; u++) {
          const int id = t + u * 256;
          const int r  = id >> 4;
          const int c4 = (id & 15) << 2;
          pa[u] = *(const float4*)&X[(size_t)(b * TSEQ + jt * 64 + r) * CDIM + k0 + c4];
        }
#pragma unroll
        for (int u = 0; u < 8; u++) {
          const int id = t + u * 256;
          const int r  = id >> 4;                 // 0..127
          const int c4 = (id & 15) << 2;
          const int wrow = (r < 64) ? (512 + h * 64 + r) : (1024 + h * 64 + (r - 64));
          pb[u] = *(const float4*)&W_attn[(size_t)wrow * CDIM + k0 + c4];
        }
      };

      prefetch(0);
      for (int kb = 0; kb < CDIM / 64; kb++) {
        __syncthreads();
#pragma unroll
        for (int u = 0; u < 4; u++) {
          const int id = t + u * 256;
          const int r  = id >> 4;
          const int c4 = (id & 15) << 2;
          ushort4 ah;
          ah.x = b16(pa[u].x); ah.y = b16(pa[u].y); ah.z = b16(pa[u].z); ah.w = b16(pa[u].w);
          *(ushort4*)&a_s[r][c4] = ah;
        }
#pragma unroll
        for (int u = 0; u < 8; u++) {
          const int id = t + u * 256;
          const int r  = id >> 4;
          const int c4 = (id & 15) << 2;
          ushort4 bhv;
          bhv.x = b16(pb[u].x); bhv.y = b16(pb[u].y); bhv.z = b16(pb[u].z); bhv.w = b16(pb[u].w);
          *(ushort4*)&b_s[r][c4] = bhv;
        }
        __syncthreads();
        if (kb + 1 < CDIM / 64) prefetch((kb + 1) * 64);

#pragma unroll
        for (int ks = 0; ks < 2; ks++) {
          const int fk = ks * 32 + ((l >> 4) << 3);
          bf16x8 fa[2], fb[4];
#pragma unroll
          for (int mt = 0; mt < 2; mt++) fa[mt] = *(const bf16x8*)&a_s[wm + mt * 16 + fr][fk];
#pragma unroll
          for (int nt = 0; nt < 4; nt++) fb[nt] = *(const bf16x8*)&b_s[wn + nt * 16 + fr][fk];
#pragma unroll
          for (int mt = 0; mt < 2; mt++)
#pragma unroll
            for (int nt = 0; nt < 4; nt++)
              acc[mt][nt] = __builtin_amdgcn_mfma_f32_16x16x32_bf16(fa[mt], fb[nt], acc[mt][nt], 0, 0, 0);
        }
      }

      // Epilogue: K -> k_all[token][d], V -> vt_all[d][token] (bias added).
#pragma unroll
      for (int nt = 0; nt < 4; nt++) {
        const int col = wn + nt * 16 + cl;       // 0..127 (wave-uniform region)
        if (col < 64) {
          const float bv = b_attn[512 + h * 64 + col];
#pragma unroll
          for (int mt = 0; mt < 2; mt++) {
            const int row = wm + mt * 16 + rq;
#pragma unroll
            for (int r = 0; r < 4; r++)
              k_all[jt * 64 + row + r][col] = b16(acc[mt][nt][r] + bv);
          }
        } else {
          const int d = col - 64;
          const float bv = b_attn[1024 + h * 64 + d];
#pragma unroll
          for (int mt = 0; mt < 2; mt++) {
            const int row = wm + mt * 16 + rq;
#pragma unroll
            for (int r = 0; r < 4; r++)
              vt_all[d][jt * 64 + row + r] = b16(acc[mt][nt][r] + bv);
          }
        }
      }
    }
  }

  // ===== Phase A2: Q tile (64 tokens x 64 d), pre-scaled 0.125 =============
  {
    const int wm = (w >> 1) * 32, wn = (w & 1) * 32;
    f32x4 acc[2][2];
#pragma unroll
    for (int i = 0; i < 2; i++)
#pragma unroll
      for (int j = 0; j < 2; j++) acc[i][j] = (f32x4){0.f, 0.f, 0.f, 0.f};

    float4 pa[4], pb[4];
    auto prefetch = [&](int k0) {
#pragma unroll
      for (int u = 0; u < 4; u++) {
        const int id = t + u * 256;
        const int r  = id >> 4;
        const int c4 = (id & 15) << 2;
        pa[u] = *(const float4*)&X[(size_t)(b * TSEQ + qp * 64 + r) * CDIM + k0 + c4];
        pb[u] = *(const float4*)&W_attn[(size_t)(h * 64 + r) * CDIM + k0 + c4];
      }
    };

    prefetch(0);
    for (int kb = 0; kb < CDIM / 64; kb++) {
      __syncthreads();
#pragma unroll
      for (int u = 0; u < 4; u++) {
        const int id = t + u * 256;
        const int r  = id >> 4;
        const int c4 = (id & 15) << 2;
        ushort4 ah;
        ah.x = b16(pa[u].x); ah.y = b16(pa[u].y); ah.z = b16(pa[u].z); ah.w = b16(pa[u].w);
        *(ushort4*)&a_s[r][c4] = ah;
        ushort4 bhv;
        bhv.x = b16(pb[u].x); bhv.y = b16(pb[u].y); bhv.z = b16(pb[u].z); bhv.w = b16(pb[u].w);
        *(ushort4*)&b_s[r][c4] = bhv;
      }
      __syncthreads();
      if (kb + 1 < CDIM / 64) prefetch((kb + 1) * 64);

#pragma unroll
      for (int ks = 0; ks < 2; ks++) {
        const int fk = ks * 32 + ((l >> 4) << 3);
        bf16x8 fa[2], fb[2];
#pragma unroll
        for (int mt = 0; mt < 2; mt++) fa[mt] = *(const bf16x8*)&a_s[wm + mt * 16 + fr][fk];
#pragma unroll
        for (int nt = 0; nt < 2; nt++) fb[nt] = *(const bf16x8*)&b_s[wn + nt * 16 + fr][fk];
#pragma unroll
        for (int mt = 0; mt < 2; mt++)
#pragma unroll
          for (int nt = 0; nt < 2; nt++)
            acc[mt][nt] = __builtin_amdgcn_mfma_f32_16x16x32_bf16(fa[mt], fb[nt], acc[mt][nt], 0, 0, 0);
      }
    }

#pragma unroll
    for (int nt = 0; nt < 2; nt++) {
      const int col = wn + nt * 16 + cl;         // 0..63
      const float bv = b_attn[h * 64 + col];
#pragma unroll
      for (int mt = 0; mt < 2; mt++) {
        const int row = wm + mt * 16 + rq;
#pragma unroll
        for (int r = 0; r < 4; r++)
          q_s[row + r][col] = b16((acc[mt][nt][r] + bv) * 0.125f);
      }
    }
  }

  __syncthreads();   // phase A -> B: all of q_s/k_all/vt_all visible

  // ===== Phase B: verified attention body, operands from LDS ===============
  {
    const int half = w >> 1;
    const int ww   = w & 1;
    const int q0   = qp * 64 + half * 32;
    const float NEG = -1e30f;

    const int m  = l & 15;
    const int q4 = l >> 4;
    const int ko = q4 << 3;

    bf16x8 qf[2];
#pragma unroll
    for (int kb = 0; kb < 2; kb++)
      qf[kb] = *(const bf16x8*)&q_s[half * 32 + ww * 16 + m][kb * 32 + ko];

    f32x4 acc_y[4];
    float m_i[4], Zp[4];
#pragma unroll
    for (int r = 0; r < 4; r++) {
      acc_y[r] = (f32x4){0.f, 0.f, 0.f, 0.f};
      m_i[r] = NEG; Zp[r] = 0.f;
    }

    for (int jt = 0; jt < ntiles; jt++) {
      __syncthreads();   // p_s reuse guard (prior PV reads drained)

      f32x4 s[4];
#pragma unroll
      for (int nt = 0; nt < 4; nt++) s[nt] = (f32x4){0.f, 0.f, 0.f, 0.f};
#pragma unroll
      for (int nt = 0; nt < 4; nt++)
#pragma unroll
        for (int kb = 0; kb < 2; kb++) {
          const bf16x8 kf = *(const bf16x8*)&k_all[jt * 64 + nt * 16 + m][kb * 32 + ko];
          s[nt] = __builtin_amdgcn_mfma_f32_16x16x32_bf16(qf[kb], kf, s[nt], 0, 0, 0);
        }

      const bool diag = (jt == ntiles - 1);
#pragma unroll
      for (int reg = 0; reg < 4; reg++) {
        const int i = q0 + ww * 16 + q4 * 4 + reg;
        float pvv[4];
        float vmax = NEG;
#pragma unroll
        for (int nt = 0; nt < 4; nt++) {
          float sv = s[nt][reg];
          if (diag && (jt * 64 + nt * 16 + m) > i) sv = NEG;
          pvv[nt] = sv;
          vmax = fmaxf(vmax, sv);
        }
        vmax = fmaxf(vmax, __shfl_xor(vmax, 1));
        vmax = fmaxf(vmax, __shfl_xor(vmax, 2));
        vmax = fmaxf(vmax, __shfl_xor(vmax, 4));
        vmax = fmaxf(vmax, __shfl_xor(vmax, 8));
        const float mnew  = fmaxf(m_i[reg], vmax);
        const float alpha = __expf(m_i[reg] - mnew);
        m_i[reg] = mnew;
        float zs = 0.f;
#pragma unroll
        for (int nt = 0; nt < 4; nt++) {
          const float p = __expf(pvv[nt] - mnew);
          p_s[w][q4 * 4 + reg][nt * 16 + m] = b16(p);
          zs += p;
        }
        Zp[reg] = Zp[reg] * alpha + zs;
#pragma unroll
        for (int nt2 = 0; nt2 < 4; nt2++) acc_y[nt2][reg] *= alpha;
      }
      __syncthreads();   // cross-lane P round-trip needs a real barrier

#pragma unroll
      for (int kb2 = 0; kb2 < 2; kb2++) {
        const bf16x8 pf = *(const bf16x8*)&p_s[w][m][kb2 * 32 + ko];
#pragma unroll
        for (int nt2 = 0; nt2 < 4; nt2++) {
          const bf16x8 vf = *(const bf16x8*)&vt_all[nt2 * 16 + m][jt * 64 + kb2 * 32 + ko];
          acc_y[nt2] = __builtin_amdgcn_mfma_f32_16x16x32_bf16(pf, vf, acc_y[nt2], 0, 0, 0);
        }
      }
    }

#pragma unroll
    for (int reg = 0; reg < 4; reg++) {
      float z = Zp[reg];
      z += __shfl_xor(z, 1);
      z += __shfl_xor(z, 2);
      z += __shfl_xor(z, 4);
      z += __shfl_xor(z, 8);
      const float inv = 1.0f / z;
      const int i = q0 + ww * 16 + q4 * 4 + reg;
#pragma unroll
      for (int nt2 = 0; nt2 < 4; nt2++)
        y[((size_t)(b * TSEQ + i)) * CDIM + h * 64 + nt2 * 16 + m] =
            b16(acc_y[nt2][reg] * inv);
    }
  }
}

// ---------------------------------------------------------------------------
// Proj GEMM — verified R10/R12. 32x64 tile, grid (64,8). Writes penalty.
// ---------------------------------------------------------------------------
__global__ __launch_bounds__(256) void proj_mfma(
    const unsigned short* __restrict__ A, const float* __restrict__ B,
    const float* __restrict__ bias, float* __restrict__ C) {
  __shared__ unsigned short a_s[32][68];
  __shared__ unsigned short b_s[64][68];

  const int t  = threadIdx.x;
  if (blockIdx.x == 0 && blockIdx.y == 0 && t == 0) {
    const double log_1em8 = -18.420680743952367;
    C[(size_t)BT * CDIM] = (float)(-0.01 * (16384.0 * log_1em8)); // 3018.0443
  }
  const int m0 = blockIdx.x * 32;
  const int n0 = blockIdx.y * 64;
  const int w  = t >> 6, l = t & 63;
  const int wm = (w >> 1) * 16, wn = (w & 1) * 32;

  f32x4 acc[2];
#pragma unroll
  for (int j = 0; j < 2; j++) acc[j] = (f32x4){0.f, 0.f, 0.f, 0.f};

  uint4  pa;
  float4 pb[4];
  auto prefetch = [&](int k0) {
    {
      const int r = t >> 3, c8 = (t & 7) << 3;
      pa = *(const uint4*)(A + (size_t)(m0 + r) * CDIM + k0 + c8);
    }
#pragma unroll
    for (int u = 0; u < 4; u++) {
      const int id = t + u * 256;
      const int r = id >> 4, c4 = (id & 15) << 2;
      pb[u] = *(const float4*)&B[(size_t)(n0 + r) * CDIM + k0 + c4];
    }
  };

  prefetch(0);
  for (int kb = 0; kb < CDIM / 64; kb++) {
    __syncthreads();
    {
      const int r = t >> 3, c8 = (t & 7) << 3;
      *(uint4*)&a_s[r][c8] = pa;
    }
#pragma unroll
    for (int u = 0; u < 4; u++) {
      const int id = t + u * 256;
      const int r = id >> 4, c4 = (id & 15) << 2;
      ushort4 bh;
      bh.x = b16(pb[u].x); bh.y = b16(pb[u].y); bh.z = b16(pb[u].z); bh.w = b16(pb[u].w);
      *(ushort4*)&b_s[r][c4] = bh;
    }
    __syncthreads();
    if (kb + 1 < CDIM / 64) prefetch((kb + 1) * 64);

#pragma unroll
    for (int ks = 0; ks < 2; ks++) {
      const int fr = l & 15;
      const int fk = ks * 32 + ((l >> 4) << 3);
      const bf16x8 fa = *(const bf16x8*)&a_s[wm + fr][fk];
      bf16x8 fb2[2];
#pragma unroll
      for (int nt = 0; nt < 2; nt++) fb2[nt] = *(const bf16x8*)&b_s[wn + nt * 16 + fr][fk];
#pragma unroll
      for (int nt = 0; nt < 2; nt++)
        acc[nt] = __builtin_amdgcn_mfma_f32_16x16x32_bf16(fa, fb2[nt], acc[nt], 0, 0, 0);
    }
  }

  const int cl = l & 15, rq = (l >> 4) << 2;
#pragma unroll
  for (int nt = 0; nt < 2; nt++) {
    const int col = n0 + wn + nt * 16 + cl;
    const float bv = bias[col];
    const int row = m0 + wm + rq;
#pragma unroll
    for (int r = 0; r < 4; r++)
      C[(size_t)(row + r) * CDIM + col] = acc[nt][r] + bv;
  }
}

extern "C" void kernel_launch(void* const* d_in, const int* in_sizes, int n_in,
                              void* d_out, int out_size, void* d_ws, size_t ws_size,
                              hipStream_t stream) {
  const float* x      = (const float*)d_in[0];
  const float* W_attn = (const float*)d_in[1];
  const float* b_attn = (const float*)d_in[2];
  const float* W_proj = (const float*)d_in[3];
  const float* b_proj = (const float*)d_in[4];
  float* out = (float*)d_out;

  char* wsb = (char*)d_ws;
  unsigned short* y_bf = (unsigned short*)wsb;   // 2.10 MB

  // 1) fused per-head qkv + flash attention -> y (bf16)
  qkv_attn_fused<<<dim3(4, 64), 256, 0, stream>>>(x, W_attn, b_attn, y_bf);

  // 2) out = y @ W_proj^T + b_proj; writes penalty scalar
  proj_mfma<<<dim3(64, 8), 256, 0, stream>>>(y_bf, W_proj, b_proj, out);
}